// Round 11
// baseline (426.918 us; speedup 1.0000x reference)
//
#include <hip/hip_runtime.h>
#include <math.h>

typedef __attribute__((ext_vector_type(8))) short short8;
typedef __attribute__((ext_vector_type(4))) float f32x4;
typedef __attribute__((ext_vector_type(4))) int i32x4;

__device__ __forceinline__ float b2f(short s) {
    unsigned u = ((unsigned)(unsigned short)s) << 16;
    return __builtin_bit_cast(float, u);
}
__device__ __forceinline__ short f2b(float f) {
    unsigned u = __builtin_bit_cast(unsigned, f);
    u += 0x7FFFu + ((u >> 16) & 1u);
    return (short)(u >> 16);
}
// packed f32x2 -> bf16x2 (RNE), gfx950 has no builtin for this (guide T12)
__device__ __forceinline__ int cvtpk(float lo, float hi) {
    int d;
    asm("v_cvt_pk_bf16_f32 %0, %1, %2" : "=v"(d) : "v"(lo), "v"(hi));
    return d;
}
// async global->LDS, 16B per lane; lds base must be wave-uniform
__device__ __forceinline__ void gload16(const void* g, void* l) {
    __builtin_amdgcn_global_load_lds(
        (const __attribute__((address_space(1))) unsigned int*)g,
        (__attribute__((address_space(3))) unsigned int*)l, 16, 0, 0);
}

// ================= fused preprocessing: 4 transposes + bias_pre + ln1 =================
__device__ __forceinline__ void transpose_body(
    const float* __restrict__ src, short* __restrict__ dst,
    int K, int N, int bx, int by, short (*tile)[33])
{
    const int kt = by * 32, nt = bx * 32;
    const int tx = threadIdx.x & 31, ty = threadIdx.x >> 5;
    #pragma unroll
    for (int i = 0; i < 4; i++) {
        int k = kt + ty + 8 * i, n = nt + tx;
        short v = 0;
        if (k < K && n < N) v = f2b(src[(size_t)k * N + n]);
        tile[ty + 8 * i][tx] = v;
    }
    __syncthreads();
    #pragma unroll
    for (int i = 0; i < 4; i++) {
        int n = nt + ty + 8 * i, k = kt + tx;
        if (n < N && k < K) dst[(size_t)n * K + k] = tile[tx][ty + 8 * i];
    }
}

// bias+mask in SWAPPED-QK C-fragment layout:
// btfm[cls][head][rt][kk][h][lane][4]; q-row i = rt*16+(lane&15),
// key j = kk*32 + 8*(lane>>4) + 4*h + r; -100 when shift-groups differ.
__device__ __forceinline__ void bias_body(const float* __restrict__ btab,
                                          float* __restrict__ btf, int blk)
{
    int idx = blk * 256 + threadIdx.x;           // over 4*12*22*11*2*64
    int lane = idx & 63; int rem = idx >> 6;
    int h = rem & 1; rem >>= 1;
    int kk = rem % 11; rem /= 11;
    int rt = rem % 22; rem /= 22;
    int head = rem % 12; int cls = rem / 12;
    int i = rt * 16 + (lane & 15);
    int jbase = kk * 32 + (lane >> 4) * 8 + h * 4;
    f32x4 out;
    #pragma unroll
    for (int r = 0; r < 4; r++) {
        int jj = jbase + r;
        float v;
        if (jj >= 344) v = -1e30f;
        else if (i >= 344 || i == 0 || jj == 0) v = 0.f;
        else {
            int ti = i - 1, tj = jj - 1;
            int ai = ti / 49, bi = (ti % 49) / 7, ci = ti % 7;
            int aj = tj / 49, bj = (tj % 49) / 7, cj = tj % 7;
            int id3 = (ai - aj + 6) * 20 + (bi - bj + 6) * 13 + (ci - cj + 6);
            v = btab[id3 * 12 + head];
            int gsi = (ai < 4) ? 1 : 2, gsj = (aj < 4) ? 1 : 2;
            int ghi = (cls & 2) ? ((bi < 4) ? 1 : 2) : 0;
            int ghj = (cls & 2) ? ((bj < 4) ? 1 : 2) : 0;
            int gwi = (cls & 1) ? ((ci < 4) ? 1 : 2) : 0;
            int gwj = (cls & 1) ? ((cj < 4) ? 1 : 2) : 0;
            if (gsi != gsj || ghi != ghj || gwi != gwj) v -= 100.f;
        }
        out[r] = v;
    }
    *(f32x4*)&btf[(size_t)idx * 4] = out;
}

__device__ __forceinline__ void ln1_body(
    const float* __restrict__ x, const float* __restrict__ gt,
    const float* __restrict__ g, const float* __restrict__ b,
    short* __restrict__ xc, int blk)
{
    int wid = threadIdx.x >> 6, lane = threadIdx.x & 63;
    int r = blk * 4 + wid;
    int w = r / 344, n = r - w * 344;
    if (n == 0) {
        #pragma unroll
        for (int i = 0; i < 6; i++) {
            int c = lane + i * 64;
            xc[(size_t)r * 384 + c] = f2b(gt[(size_t)w * 384 + c]);
        }
        return;
    }
    int t = n - 1;
    int a = t / 49, rm = t - a * 49, bb = rm / 7, cc = rm - bb * 7;
    int hw = w >> 3, ww = w & 7;
    int s = (a < 4) ? a + 3 : a - 4;
    int h = hw * 7 + bb + 3; if (h >= 56) h -= 56;
    int wd = ww * 7 + cc + 3; if (wd >= 56) wd -= 56;
    const float* row = x + (size_t)((s * 56 + h) * 56 + wd) * 384;
    float v[6]; float sum = 0.f;
    #pragma unroll
    for (int i = 0; i < 6; i++) { v[i] = row[lane + i * 64]; sum += v[i]; }
    #pragma unroll
    for (int off = 32; off >= 1; off >>= 1) sum += __shfl_xor(sum, off);
    float mu = sum * (1.0f / 384.0f);
    float vs = 0.f;
    #pragma unroll
    for (int i = 0; i < 6; i++) { float d = v[i] - mu; vs += d * d; }
    #pragma unroll
    for (int off = 32; off >= 1; off >>= 1) vs += __shfl_xor(vs, off);
    float rstd = rsqrtf(vs * (1.0f / 384.0f) + 1e-5f);
    #pragma unroll
    for (int i = 0; i < 6; i++) {
        int c = lane + i * 64;
        float o = (v[i] - mu) * rstd * g[c] + b[c];
        xc[(size_t)r * 384 + c] = f2b(o);
    }
}

// block ranges: [0,432) qkvT | [432,576) projT | [576,1152) fc1T | [1152,1728) fc2T
//             | [1728,7536) bias | [7536,13040) ln1
__global__ __launch_bounds__(256) void prep_kernel(
    const float* __restrict__ qkv_w, const float* __restrict__ proj_w,
    const float* __restrict__ fc1_w, const float* __restrict__ fc2_w,
    short* __restrict__ wt_qkv, short* __restrict__ wt_proj,
    short* __restrict__ wt_fc1, short* __restrict__ wt_fc2,
    const float* __restrict__ btab, float* __restrict__ btf,
    const float* __restrict__ x, const float* __restrict__ gt,
    const float* __restrict__ n1g, const float* __restrict__ n1b,
    short* __restrict__ xc)
{
    __shared__ short tile[32][33];
    int b = blockIdx.x;
    if (b < 432)  { transpose_body(qkv_w,  wt_qkv,  384, 1152, b % 36, b / 36, tile); return; }
    b -= 432;
    if (b < 144)  { transpose_body(proj_w, wt_proj, 384,  384, b % 12, b / 12, tile); return; }
    b -= 144;
    if (b < 576)  { transpose_body(fc1_w,  wt_fc1,  384, 1536, b % 48, b / 48, tile); return; }
    b -= 576;
    if (b < 576)  { transpose_body(fc2_w,  wt_fc2, 1536,  384, b % 12, b / 12, tile); return; }
    b -= 576;
    if (b < 5808) { bias_body(btab, btf, b); return; }
    b -= 5808;
    ln1_body(x, gt, n1g, n1b, xc, b);
}

// ------------ LN2 over bf16 x_new, token-major, out bf16 ------------
__global__ __launch_bounds__(256) void ln2_kernel(
    const short* __restrict__ xn, const float* __restrict__ g,
    const float* __restrict__ b, short* __restrict__ out)
{
    int wid = threadIdx.x >> 6, lane = threadIdx.x & 63;
    int r = blockIdx.x * 4 + wid;
    const short* row = xn + (size_t)r * 384;
    float v[6]; float sum = 0.f;
    #pragma unroll
    for (int i = 0; i < 6; i++) { v[i] = b2f(row[lane + i * 64]); sum += v[i]; }
    #pragma unroll
    for (int off = 32; off >= 1; off >>= 1) sum += __shfl_xor(sum, off);
    float mu = sum * (1.0f / 384.0f);
    float vs = 0.f;
    #pragma unroll
    for (int i = 0; i < 6; i++) { float d = v[i] - mu; vs += d * d; }
    #pragma unroll
    for (int off = 32; off >= 1; off >>= 1) vs += __shfl_xor(vs, off);
    float rstd = rsqrtf(vs * (1.0f / 384.0f) + 1e-5f);
    #pragma unroll
    for (int i = 0; i < 6; i++) {
        int c = lane + i * 64;
        float o = (v[i] - mu) * rstd * g[c] + b[c];
        out[(size_t)r * 384 + c] = f2b(o);
    }
}

// ------- 256x128-tile bf16 MFMA GEMM, BK=64, single-buffer 2-barrier (R6 proven) -------
// NOTE (R1/R2/R7/R8 post-mortems): do NOT double-buffer THIS structure, do NOT set
// min-waves. Latency hiding here = blocks/CU TLP (2/CU).
template<int EPI, bool QS>
__global__ __launch_bounds__(512) void gemm256(
    const short* __restrict__ A, const short* __restrict__ BT,
    const float* __restrict__ bias, void* __restrict__ Out,
    const void* __restrict__ P0, void* __restrict__ P1,
    int M, int N, int K)
{
    __shared__ short As[256 * 64];
    __shared__ short Bs[128 * 64];
    const int m0 = blockIdx.y * 256, n0 = blockIdx.x * 128;
    const int tid = threadIdx.x;
    const int wid = tid >> 6, lane = tid & 63;
    const int wm = wid >> 1, wn = wid & 1;           // 4M x 2N waves
    const int l15 = lane & 15, quad = lane >> 4;

    f32x4 acc[4][4];
    #pragma unroll
    for (int i = 0; i < 4; i++)
        #pragma unroll
        for (int j = 0; j < 4; j++) acc[i][j] = (f32x4){0.f, 0.f, 0.f, 0.f};

    const int trow = tid >> 3;                 // 0..63
    const int cs = tid & 7;
    const int gc = cs ^ (trow & 7);
    const short* Ag[4]; const short* Bg[2];
    #pragma unroll
    for (int j = 0; j < 4; j++) {
        int ar = m0 + j * 64 + trow; if (ar >= M) ar = M - 1;
        Ag[j] = A + (size_t)ar * K + gc * 8;
    }
    #pragma unroll
    for (int j = 0; j < 2; j++) {
        int br = n0 + j * 64 + trow; if (br >= N) br = N - 1;
        Bg[j] = BT + (size_t)br * K + gc * 8;
    }
    short* AsW[4]; short* BsW[2];
    #pragma unroll
    for (int j = 0; j < 4; j++) AsW[j] = &As[(j * 64 + wid * 8) * 64];
    #pragma unroll
    for (int j = 0; j < 2; j++) BsW[j] = &Bs[(j * 64 + wid * 8) * 64];

    int arow[4], brow[4];
    #pragma unroll
    for (int mt = 0; mt < 4; mt++) arow[mt] = wm * 64 + mt * 16 + l15;
    #pragma unroll
    for (int nt = 0; nt < 4; nt++) brow[nt] = wn * 64 + nt * 16 + l15;

    for (int ks = 0; ks < K; ks += 64) {
        #pragma unroll
        for (int j = 0; j < 4; j++) gload16(Ag[j] + ks, AsW[j]);
        #pragma unroll
        for (int j = 0; j < 2; j++) gload16(Bg[j] + ks, BsW[j]);
        __syncthreads();
        #pragma unroll
        for (int ko = 0; ko < 2; ko++) {
            short8 af[4], bf[4];
            #pragma unroll
            for (int mt = 0; mt < 4; mt++)
                af[mt] = *(const short8*)&As[arow[mt] * 64
                         + (((ko * 4 + quad) ^ (l15 & 7)) * 8)];
            #pragma unroll
            for (int nt = 0; nt < 4; nt++)
                bf[nt] = *(const short8*)&Bs[brow[nt] * 64
                         + (((ko * 4 + quad) ^ (l15 & 7)) * 8)];
            #pragma unroll
            for (int mt = 0; mt < 4; mt++)
                #pragma unroll
                for (int nt = 0; nt < 4; nt++)
                    acc[mt][nt] = __builtin_amdgcn_mfma_f32_16x16x32_bf16(
                        af[mt], bf[nt], acc[mt][nt], 0, 0, 0);
        }
        __syncthreads();
    }

    #pragma unroll
    for (int mt = 0; mt < 4; mt++) {
        #pragma unroll
        for (int nt = 0; nt < 4; nt++) {
            #pragma unroll
            for (int r = 0; r < 4; r++) {
                int row = m0 + wm * 64 + mt * 16 + quad * 4 + r;
                int col = n0 + wn * 64 + nt * 16 + l15;
                if (row >= M) continue;
                float v = acc[mt][nt][r] + bias[col];
                if (EPI == 0) {
                    if (QS && col < 384) v *= 0.17677669529663687f;
                    ((short*)Out)[(size_t)row * N + col] = f2b(v);
                } else if (EPI == 1) {
                    float u2 = v * v;
                    float w  = v * fmaf(0.07135481633f, u2, 1.5957691216f);
                    float e  = __expf(w);
                    float t2 = __builtin_amdgcn_rcpf(1.0f + e);
                    v = v - v * t2;
                    ((short*)Out)[(size_t)row * N + col] = f2b(v);
                } else if (EPI == 2) {
                    int w = row / 344, n = row - w * 344;
                    if (n == 0) {
                        ((float*)P1)[(size_t)w * 384 + col] = v;
                    } else {
                        int t2 = n - 1;
                        int a = t2 / 49, rm = t2 - a * 49;
                        int bb = rm / 7, cc = rm - bb * 7;
                        int hw = w >> 3, ww = w & 7;
                        int s = (a < 4) ? a + 3 : a - 4;
                        int h = hw * 7 + bb + 3; if (h >= 56) h -= 56;
                        int wd = ww * 7 + cc + 3; if (wd >= 56) wd -= 56;
                        size_t td = (size_t)((s * 56 + h) * 56 + wd) * 384 + col;
                        ((short*)Out)[td] = f2b(v + ((const float*)P0)[td]);
                    }
                } else {  // EPI 3: residual read from bf16 xnew
                    v += b2f(((const short*)P0)[(size_t)row * N + col]);
                    ((float*)Out)[(size_t)row * N + col] = v;
                }
            }
        }
    }
}

// ---- 256x256-tile, depth-2 K-tile ping-pong pipeline (1 block/CU by design) ----
// R11: latency hiding comes from the INTRA-block pipeline, not TLP (so the R1/R7
// occupancy-loss failure mode does not apply — there is no occupancy to lose).
// Per iter t: issue tile t+1's 8 gload16 into buf freed by t-1's barrier; compute
// tile t's 64 MFMA/wave (~1024 cyc cover/SIMD); single lgkm0+vmcnt0+barrier.
// Safety argument: at the barrier every wave's ds_reads are retired (lgkm0) and its
// t+1 loads landed (vmcnt0); post-barrier writes to buf[t&1] and reads of buf[t&1^1]
// are race-free. Index algebra identical to gemm256 (64-row rounds keep row&7==trow&7).
template<int EPI, bool QS>
__global__ __launch_bounds__(512) void gemm256x256(
    const short* __restrict__ A, const short* __restrict__ BT,
    const float* __restrict__ bias, void* __restrict__ Out,
    const void* __restrict__ P0, void* __restrict__ P1,
    int M, int N, int K)
{
    __shared__ short As[2 * 256 * 64];   // 64 KB (2 buffers)
    __shared__ short Bs[2 * 256 * 64];   // 64 KB
    const int m0 = blockIdx.y * 256, n0 = blockIdx.x * 256;
    const int tid = threadIdx.x;
    const int wid = tid >> 6, lane = tid & 63;
    const int wm = wid >> 2, wn = wid & 3;     // 2M x 4N waves, 128x64 out each
    const int l15 = lane & 15, quad = lane >> 4;

    f32x4 acc[8][4];
    #pragma unroll
    for (int i = 0; i < 8; i++)
        #pragma unroll
        for (int j = 0; j < 4; j++) acc[i][j] = (f32x4){0.f, 0.f, 0.f, 0.f};

    const int trow = tid >> 3;                 // 0..63
    const int cs = tid & 7;
    const int gc = cs ^ (trow & 7);
    const short* Ag[4]; const short* Bg[4];
    #pragma unroll
    for (int j = 0; j < 4; j++) {
        int ar = m0 + j * 64 + trow; if (ar >= M) ar = M - 1;
        Ag[j] = A + (size_t)ar * K + gc * 8;
        int br = n0 + j * 64 + trow; if (br >= N) br = N - 1;
        Bg[j] = BT + (size_t)br * K + gc * 8;
    }
    short* AsW[4]; short* BsW[4];
    #pragma unroll
    for (int j = 0; j < 4; j++) {
        AsW[j] = &As[(j * 64 + wid * 8) * 64];
        BsW[j] = &Bs[(j * 64 + wid * 8) * 64];
    }

    int arow[8], brow[4];
    #pragma unroll
    for (int mt = 0; mt < 8; mt++) arow[mt] = wm * 128 + mt * 16 + l15;   // 0..255
    #pragma unroll
    for (int nt = 0; nt < 4; nt++) brow[nt] = wn * 64 + nt * 16 + l15;    // 0..255

    const int nsteps = K >> 6;
    // prologue: stage tile 0 into buffer 0, wait, barrier (exposed once per block)
    #pragma unroll
    for (int j = 0; j < 4; j++) { gload16(Ag[j], AsW[j]); gload16(Bg[j], BsW[j]); }
    asm volatile("s_waitcnt vmcnt(0)" ::: "memory");
    __builtin_amdgcn_s_barrier();

    for (int t = 0; t < nsteps; ++t) {
        const int cur = t & 1;
        if (t + 1 < nsteps) {
            const int ks = (t + 1) << 6;
            const int ob = (cur ^ 1) << 14;     // buffer offset in shorts (16384)
            #pragma unroll
            for (int j = 0; j < 4; j++) {
                gload16(Ag[j] + ks, AsW[j] + ob);
                gload16(Bg[j] + ks, BsW[j] + ob);
            }
        }
        const short* Ab = &As[cur << 14];
        const short* Bb = &Bs[cur << 14];
        #pragma unroll
        for (int ko = 0; ko < 2; ko++) {
            short8 af[8], bf[4];
            #pragma unroll
            for (int mt = 0; mt < 8; mt++)
                af[mt] = *(const short8*)&Ab[arow[mt] * 64
                         + (((ko * 4 + quad) ^ (l15 & 7)) * 8)];
            #pragma unroll
            for (int nt = 0; nt < 4; nt++)
                bf[nt] = *(const short8*)&Bb[brow[nt] * 64
                         + (((ko * 4 + quad) ^ (l15 & 7)) * 8)];
            #pragma unroll
            for (int mt = 0; mt < 8; mt++)
                #pragma unroll
                for (int nt = 0; nt < 4; nt++)
                    acc[mt][nt] = __builtin_amdgcn_mfma_f32_16x16x32_bf16(
                        af[mt], bf[nt], acc[mt][nt], 0, 0, 0);
        }
        // single sync point per K-tile: my reads retired + my t+1 loads landed
        asm volatile("s_waitcnt vmcnt(0) lgkmcnt(0)" ::: "memory");
        __builtin_amdgcn_s_barrier();
    }

    #pragma unroll
    for (int mt = 0; mt < 8; mt++) {
        #pragma unroll
        for (int nt = 0; nt < 4; nt++) {
            #pragma unroll
            for (int r = 0; r < 4; r++) {
                int row = m0 + wm * 128 + mt * 16 + quad * 4 + r;
                int col = n0 + wn * 64 + nt * 16 + l15;
                if (row >= M) continue;
                float v = acc[mt][nt][r] + bias[col];
                if (EPI == 1) {
                    float u2 = v * v;
                    float w  = v * fmaf(0.07135481633f, u2, 1.5957691216f);
                    float e  = __expf(w);
                    float t2 = __builtin_amdgcn_rcpf(1.0f + e);
                    v = v - v * t2;
                }
                ((short*)Out)[(size_t)row * N + col] = f2b(v);
            }
        }
    }
}

// -------- fused windowed attention, swapped-QK in-register softmax --------
__global__ __launch_bounds__(256) void attn_kernel(
    const short* __restrict__ qkv, const float* __restrict__ btfm,
    short* __restrict__ attn_out)
{
    __shared__ short KT[352 * 32];   // 22528B permuted K rows, chunk-swizzled
    __shared__ short VT[32 * 360];   // 23040B V^T: [dd][key]
    const int orig = blockIdx.x;
    const int nid = (orig & 7) * 96 + (orig >> 3);   // bijective, 768 = 8*96
    const int head = nid >> 6, w = nid & 63;         // head-major within XCD chunk
    const int cls = (((w >> 3) == 7) ? 2 : 0) | (((w & 7) == 7) ? 1 : 0);
    const int tid = threadIdx.x;
    const int wid = tid >> 6, lane = tid & 63;
    const int l15 = lane & 15, quad = lane >> 4;
    const size_t base = (size_t)w * 344 * 1152 + head * 32;

    for (int c = tid; c < 352 * 4; c += 256) {
        int n = c >> 2, ch = c & 3;
        short8 v8 = (short8){0,0,0,0,0,0,0,0};
        if (n < 344) v8 = *(const short8*)&qkv[base + 384 + (size_t)n * 1152 + ch * 8];
        int j32 = n & 31, kk = n >> 5;
        int R = kk * 32 + ((j32 >> 2) & 1) * 16 + ((j32 >> 3) << 2) + (j32 & 3);
        *(short8*)&KT[R * 32 + ((ch ^ ((R >> 1) & 3)) * 8)] = v8;
    }
    for (int e = tid; e < 344 * 4; e += 256) {
        int key = e >> 2, g = (e & 3) * 8;
        short8 v8 = *(const short8*)&qkv[base + 768 + (size_t)key * 1152 + g];
        #pragma unroll
        for (int i = 0; i < 8; i++) VT[(g + i) * 360 + key] = v8[i];
    }
    for (int e = tid; e < 8 * 32; e += 256) {
        int key = 344 + (e >> 5), dd = e & 31;
        VT[dd * 360 + key] = 0;
    }
    __syncthreads();

    const float* bh = btfm + (size_t)(cls * 12 + head) * (22 * 11 * 2 * 256);
    const int swq = (l15 >> 1) & 3;
    const int kOff = l15 * 32 + ((quad ^ swq) * 8);   // + kk*1024 + h*512

    for (int j = wid; j < 11; j += 4) {
        const int rtA = 2 * j, rtB = rtA + 1;
        const int qrA = rtA * 16 + l15;                  // <= 335, valid
        int qrB = rtB * 16 + l15; if (qrB > 343) qrB = 343;
        short8 afA = *(const short8*)&qkv[base + (size_t)qrA * 1152 + quad * 8];
        short8 afB = *(const short8*)&qkv[base + (size_t)qrB * 1152 + quad * 8];

        f32x4 oA0 = {0,0,0,0}, oA1 = {0,0,0,0}, oB0 = {0,0,0,0}, oB1 = {0,0,0,0};
        float lA = 0.f, lB = 0.f;
        const float* bhA = bh + (size_t)rtA * (11 * 2 * 256) + lane * 4;
        const float* bhB = bh + (size_t)rtB * (11 * 2 * 256) + lane * 4;

        f32x4 nA0 = *(const f32x4*)&bhA[0];
        f32x4 nA1 = *(const f32x4*)&bhA[256];
        f32x4 nB0 = *(const f32x4*)&bhB[0];
        f32x4 nB1 = *(const f32x4*)&bhB[256];

        for (int kk = 0; kk < 11; kk++) {
            f32x4 cA0 = nA0, cA1 = nA1, cB0 = nB0, cB1 = nB1;
            int kn = (kk < 10) ? kk + 1 : 10;
            nA0 = *(const f32x4*)&bhA[(kn * 2 + 0) * 256];
            nA1 = *(const f32x4*)&bhA[(kn * 2 + 1) * 256];
            nB0 = *(const f32x4*)&bhB[(kn * 2 + 0) * 256];
            nB1 = *(const f32x4*)&bhB[(kn * 2 + 1) * 256];

            short8 k0 = *(const short8*)&KT[kk * 1024 + kOff];
            short8 k1 = *(const short8*)&KT[kk * 1024 + 512 + kOff];
            __builtin_amdgcn_s_setprio(1);
            f32x4 sA0 = __builtin_amdgcn_mfma_f32_16x16x32_bf16(k0, afA, cA0, 0, 0, 0);
            f32x4 sA1 = __builtin_amdgcn_mfma_f32_16x16x32_bf16(k1, afA, cA1, 0, 0, 0);
            f32x4 sB0 = __builtin_amdgcn_mfma_f32_16x16x32_bf16(k0, afB, cB0, 0, 0, 0);
            f32x4 sB1 = __builtin_amdgcn_mfma_f32_16x16x32_bf16(k1, afB, cB1, 0, 0, 0);
            __builtin_amdgcn_s_setprio(0);

            float a0 = __expf(sA0[0]), a1 = __expf(sA0[1]);
            float a2 = __expf(sA0[2]), a3 = __expf(sA0[3]);
            float a4 = __expf(sA1[0]), a5 = __expf(sA1[1]);
            float a6 = __expf(sA1[2]), a7 = __expf(sA1[3]);
            lA += ((a0 + a1) + (a2 + a3)) + ((a4 + a5) + (a6 + a7));
            i32x4 pkA;
            pkA[0] = cvtpk(a0, a1); pkA[1] = cvtpk(a2, a3);
            pkA[2] = cvtpk(a4, a5); pkA[3] = cvtpk(a6, a7);
            short8 paA = __builtin_bit_cast(short8, pkA);

            float b0 = __expf(sB0[0]), b1 = __expf(sB0[1]);
            float b2 = __expf(sB0[2]), b3 = __expf(sB0[3]);
            float b4 = __expf(sB1[0]), b5 = __expf(sB1[1]);
            float b6 = __expf(sB1[2]), b7 = __expf(sB1[3]);
            lB += ((b0 + b1) + (b2 + b3)) + ((b4 + b5) + (b6 + b7));
            i32x4 pkB;
            pkB[0] = cvtpk(b0, b1); pkB[1] = cvtpk(b2, b3);
            pkB[2] = cvtpk(b4, b5); pkB[3] = cvtpk(b6, b7);
            short8 paB = __builtin_bit_cast(short8, pkB);

            short8 v0 = *(const short8*)&VT[l15 * 360 + kk * 32 + quad * 8];
            short8 v1 = *(const short8*)&VT[(16 + l15) * 360 + kk * 32 + quad * 8];
            __builtin_amdgcn_s_setprio(1);
            oA0 = __builtin_amdgcn_mfma_f32_16x16x32_bf16(paA, v0, oA0, 0, 0, 0);
            oA1 = __builtin_amdgcn_mfma_f32_16x16x32_bf16(paA, v1, oA1, 0, 0, 0);
            oB0 = __builtin_amdgcn_mfma_f32_16x16x32_bf16(paB, v0, oB0, 0, 0, 0);
            oB1 = __builtin_amdgcn_mfma_f32_16x16x32_bf16(paB, v1, oB1, 0, 0, 0);
            __builtin_amdgcn_s_setprio(0);
        }

        lA += __shfl_xor(lA, 16); lA += __shfl_xor(lA, 32);
        lB += __shfl_xor(lB, 16); lB += __shfl_xor(lB, 32);
        float iA = 1.0f / lA, iB = 1.0f / lB;
        #pragma unroll
        for (int r = 0; r < 4; r++) {
            int rowA = rtA * 16 + quad * 4 + r;
            float nA = __shfl(iA, quad * 4 + r);
            float nB = __shfl(iB, quad * 4 + r);
            size_t obA = ((size_t)w * 344 + rowA) * 384 + head * 32;
            attn_out[obA + l15] = f2b(oA0[r] * nA);
            attn_out[obA + 16 + l15] = f2b(oA1[r] * nA);
            int rowB = rowA + 16;
            if (rowB < 344) {
                size_t obB = ((size_t)w * 344 + rowB) * 384 + head * 32;
                attn_out[obB + l15] = f2b(oB0[r] * nB);
                attn_out[obB + 16 + l15] = f2b(oB1[r] * nB);
            }
        }
    }
}

extern "C" void kernel_launch(void* const* d_in, const int* in_sizes, int n_in,
                              void* d_out, int out_size, void* d_ws, size_t ws_size,
                              hipStream_t stream)
{
    const float* x      = (const float*)d_in[0];
    const float* gt     = (const float*)d_in[1];
    const float* n1g    = (const float*)d_in[2];
    const float* n1b    = (const float*)d_in[3];
    const float* qkv_w  = (const float*)d_in[4];
    const float* qkv_b  = (const float*)d_in[5];
    const float* btab   = (const float*)d_in[6];
    const float* proj_w = (const float*)d_in[7];
    const float* proj_b = (const float*)d_in[8];
    const float* n2g    = (const float*)d_in[9];
    const float* n2b    = (const float*)d_in[10];
    const float* fc1_w  = (const float*)d_in[11];
    const float* fc1_b  = (const float*)d_in[12];
    const float* fc2_w  = (const float*)d_in[13];
    const float* fc2_b  = (const float*)d_in[14];

    char* ws = (char*)d_ws;
    short* wt_qkv  = (short*)(ws + 0);          //  1152x384 bf16
    short* wt_proj = (short*)(ws + 884736);     //   384x384 bf16
    short* wt_fc1  = (short*)(ws + 1179648);    //  1536x384 bf16
    short* wt_fc2  = (short*)(ws + 2359296);    //   384x1536 bf16
    short* xc      = (short*)(ws + 3538944);    // 22016x384 bf16
    short* qkvb    = (short*)(ws + 20447232);   // 22016x1152 bf16
    short* attn_o  = xc;                        // reuse (xc dead after qkv GEMM)
    short* h1      = (short*)(ws + 3538944);    // 21952x1536 bf16 (reuse xc region)
    short* xnew    = (short*)(ws + 71172096);   // 21952x384 bf16
    float* btfm    = (float*)(ws + 71172096);   // 23.8MB fp32 (dead before xnew)
    short* xnorm   = (short*)(ws + 104890368);  // 21952x384 bf16

    float* outx  = (float*)d_out;
    float* outgt = outx + (size_t)21952 * 384;

    prep_kernel<<<dim3(13040), 256, 0, stream>>>(
        qkv_w, proj_w, fc1_w, fc2_w, wt_qkv, wt_proj, wt_fc1, wt_fc2,
        btab, btfm, x, gt, n1g, n1b, xc);

    gemm256<0, true><<<dim3(9, 86), 512, 0, stream>>>(xc, wt_qkv, qkv_b, qkvb,
                                                      nullptr, nullptr, 22016, 1152, 384);

    attn_kernel<<<dim3(768), 256, 0, stream>>>(qkvb, btfm, attn_o);

    gemm256<2, false><<<dim3(3, 86), 512, 0, stream>>>(attn_o, wt_proj, proj_b, xnew,
                                                       x, outgt, 22016, 384, 384);

    ln2_kernel<<<dim3(5488), 256, 0, stream>>>(xnew, n2g, n2b, xnorm);

    // R11: FC1 on the 256x256 depth-2 pipelined kernel (N=1536 divides 256)
    gemm256x256<1, false><<<dim3(6, 86), 512, 0, stream>>>(xnorm, wt_fc1, fc1_b, h1,
                                                           nullptr, nullptr, 21952, 1536, 384);

    gemm256<3, false><<<dim3(3, 86), 512, 0, stream>>>(h1, wt_fc2, fc2_b, outx,
                                                       xnew, nullptr, 21952, 384, 1536);
}

// Round 12
// 394.604 us; speedup vs baseline: 1.0819x; 1.0819x over previous
//
#include <hip/hip_runtime.h>
#include <math.h>

typedef __attribute__((ext_vector_type(8))) short short8;
typedef __attribute__((ext_vector_type(4))) float f32x4;
typedef __attribute__((ext_vector_type(4))) int i32x4;

__device__ __forceinline__ float b2f(short s) {
    unsigned u = ((unsigned)(unsigned short)s) << 16;
    return __builtin_bit_cast(float, u);
}
__device__ __forceinline__ short f2b(float f) {
    unsigned u = __builtin_bit_cast(unsigned, f);
    u += 0x7FFFu + ((u >> 16) & 1u);
    return (short)(u >> 16);
}
// packed f32x2 -> bf16x2 (RNE), gfx950 has no builtin for this (guide T12)
__device__ __forceinline__ int cvtpk(float lo, float hi) {
    int d;
    asm("v_cvt_pk_bf16_f32 %0, %1, %2" : "=v"(d) : "v"(lo), "v"(hi));
    return d;
}
// async global->LDS, 16B per lane; lds base must be wave-uniform
__device__ __forceinline__ void gload16(const void* g, void* l) {
    __builtin_amdgcn_global_load_lds(
        (const __attribute__((address_space(1))) unsigned int*)g,
        (__attribute__((address_space(3))) unsigned int*)l, 16, 0, 0);
}

// ================= fused preprocessing: 4 transposes + bias_pre + ln1 =================
__device__ __forceinline__ void transpose_body(
    const float* __restrict__ src, short* __restrict__ dst,
    int K, int N, int bx, int by, short (*tile)[33])
{
    const int kt = by * 32, nt = bx * 32;
    const int tx = threadIdx.x & 31, ty = threadIdx.x >> 5;
    #pragma unroll
    for (int i = 0; i < 4; i++) {
        int k = kt + ty + 8 * i, n = nt + tx;
        short v = 0;
        if (k < K && n < N) v = f2b(src[(size_t)k * N + n]);
        tile[ty + 8 * i][tx] = v;
    }
    __syncthreads();
    #pragma unroll
    for (int i = 0; i < 4; i++) {
        int n = nt + ty + 8 * i, k = kt + tx;
        if (n < N && k < K) dst[(size_t)n * K + k] = tile[tx][ty + 8 * i];
    }
}

// bias+mask in SWAPPED-QK C-fragment layout:
// btfm[cls][head][rt][kk][h][lane][4]; q-row i = rt*16+(lane&15),
// key j = kk*32 + 8*(lane>>4) + 4*h + r; -100 when shift-groups differ.
__device__ __forceinline__ void bias_body(const float* __restrict__ btab,
                                          float* __restrict__ btf, int blk)
{
    int idx = blk * 256 + threadIdx.x;           // over 4*12*22*11*2*64
    int lane = idx & 63; int rem = idx >> 6;
    int h = rem & 1; rem >>= 1;
    int kk = rem % 11; rem /= 11;
    int rt = rem % 22; rem /= 22;
    int head = rem % 12; int cls = rem / 12;
    int i = rt * 16 + (lane & 15);
    int jbase = kk * 32 + (lane >> 4) * 8 + h * 4;
    f32x4 out;
    #pragma unroll
    for (int r = 0; r < 4; r++) {
        int jj = jbase + r;
        float v;
        if (jj >= 344) v = -1e30f;
        else if (i >= 344 || i == 0 || jj == 0) v = 0.f;
        else {
            int ti = i - 1, tj = jj - 1;
            int ai = ti / 49, bi = (ti % 49) / 7, ci = ti % 7;
            int aj = tj / 49, bj = (tj % 49) / 7, cj = tj % 7;
            int id3 = (ai - aj + 6) * 20 + (bi - bj + 6) * 13 + (ci - cj + 6);
            v = btab[id3 * 12 + head];
            int gsi = (ai < 4) ? 1 : 2, gsj = (aj < 4) ? 1 : 2;
            int ghi = (cls & 2) ? ((bi < 4) ? 1 : 2) : 0;
            int ghj = (cls & 2) ? ((bj < 4) ? 1 : 2) : 0;
            int gwi = (cls & 1) ? ((ci < 4) ? 1 : 2) : 0;
            int gwj = (cls & 1) ? ((cj < 4) ? 1 : 2) : 0;
            if (gsi != gsj || ghi != ghj || gwi != gwj) v -= 100.f;
        }
        out[r] = v;
    }
    *(f32x4*)&btf[(size_t)idx * 4] = out;
}

__device__ __forceinline__ void ln1_body(
    const float* __restrict__ x, const float* __restrict__ gt,
    const float* __restrict__ g, const float* __restrict__ b,
    short* __restrict__ xc, int blk)
{
    int wid = threadIdx.x >> 6, lane = threadIdx.x & 63;
    int r = blk * 4 + wid;
    int w = r / 344, n = r - w * 344;
    if (n == 0) {
        #pragma unroll
        for (int i = 0; i < 6; i++) {
            int c = lane + i * 64;
            xc[(size_t)r * 384 + c] = f2b(gt[(size_t)w * 384 + c]);
        }
        return;
    }
    int t = n - 1;
    int a = t / 49, rm = t - a * 49, bb = rm / 7, cc = rm - bb * 7;
    int hw = w >> 3, ww = w & 7;
    int s = (a < 4) ? a + 3 : a - 4;
    int h = hw * 7 + bb + 3; if (h >= 56) h -= 56;
    int wd = ww * 7 + cc + 3; if (wd >= 56) wd -= 56;
    const float* row = x + (size_t)((s * 56 + h) * 56 + wd) * 384;
    float v[6]; float sum = 0.f;
    #pragma unroll
    for (int i = 0; i < 6; i++) { v[i] = row[lane + i * 64]; sum += v[i]; }
    #pragma unroll
    for (int off = 32; off >= 1; off >>= 1) sum += __shfl_xor(sum, off);
    float mu = sum * (1.0f / 384.0f);
    float vs = 0.f;
    #pragma unroll
    for (int i = 0; i < 6; i++) { float d = v[i] - mu; vs += d * d; }
    #pragma unroll
    for (int off = 32; off >= 1; off >>= 1) vs += __shfl_xor(vs, off);
    float rstd = rsqrtf(vs * (1.0f / 384.0f) + 1e-5f);
    #pragma unroll
    for (int i = 0; i < 6; i++) {
        int c = lane + i * 64;
        float o = (v[i] - mu) * rstd * g[c] + b[c];
        xc[(size_t)r * 384 + c] = f2b(o);
    }
}

// block ranges: [0,432) qkvT | [432,576) projT | [576,1152) fc1T | [1152,1728) fc2T
//             | [1728,7536) bias | [7536,13040) ln1
__global__ __launch_bounds__(256) void prep_kernel(
    const float* __restrict__ qkv_w, const float* __restrict__ proj_w,
    const float* __restrict__ fc1_w, const float* __restrict__ fc2_w,
    short* __restrict__ wt_qkv, short* __restrict__ wt_proj,
    short* __restrict__ wt_fc1, short* __restrict__ wt_fc2,
    const float* __restrict__ btab, float* __restrict__ btf,
    const float* __restrict__ x, const float* __restrict__ gt,
    const float* __restrict__ n1g, const float* __restrict__ n1b,
    short* __restrict__ xc)
{
    __shared__ short tile[32][33];
    int b = blockIdx.x;
    if (b < 432)  { transpose_body(qkv_w,  wt_qkv,  384, 1152, b % 36, b / 36, tile); return; }
    b -= 432;
    if (b < 144)  { transpose_body(proj_w, wt_proj, 384,  384, b % 12, b / 12, tile); return; }
    b -= 144;
    if (b < 576)  { transpose_body(fc1_w,  wt_fc1,  384, 1536, b % 48, b / 48, tile); return; }
    b -= 576;
    if (b < 576)  { transpose_body(fc2_w,  wt_fc2, 1536,  384, b % 12, b / 12, tile); return; }
    b -= 576;
    if (b < 5808) { bias_body(btab, btf, b); return; }
    b -= 5808;
    ln1_body(x, gt, n1g, n1b, xc, b);
}

// ------------ LN2 over bf16 x_new, token-major, out bf16 ------------
__global__ __launch_bounds__(256) void ln2_kernel(
    const short* __restrict__ xn, const float* __restrict__ g,
    const float* __restrict__ b, short* __restrict__ out)
{
    int wid = threadIdx.x >> 6, lane = threadIdx.x & 63;
    int r = blockIdx.x * 4 + wid;
    const short* row = xn + (size_t)r * 384;
    float v[6]; float sum = 0.f;
    #pragma unroll
    for (int i = 0; i < 6; i++) { v[i] = b2f(row[lane + i * 64]); sum += v[i]; }
    #pragma unroll
    for (int off = 32; off >= 1; off >>= 1) sum += __shfl_xor(sum, off);
    float mu = sum * (1.0f / 384.0f);
    float vs = 0.f;
    #pragma unroll
    for (int i = 0; i < 6; i++) { float d = v[i] - mu; vs += d * d; }
    #pragma unroll
    for (int off = 32; off >= 1; off >>= 1) vs += __shfl_xor(vs, off);
    float rstd = rsqrtf(vs * (1.0f / 384.0f) + 1e-5f);
    #pragma unroll
    for (int i = 0; i < 6; i++) {
        int c = lane + i * 64;
        float o = (v[i] - mu) * rstd * g[c] + b[c];
        out[(size_t)r * 384 + c] = f2b(o);
    }
}

// ------- 256x128-tile bf16 MFMA GEMM, BK=64, single-buffer 2-barrier (R6 proven) -------
// NOTE (R1/R2/R7/R8/R11 post-mortems): do NOT double-buffer, do NOT graft counted-
// vmcnt pipelines, do NOT set min-waves, do NOT go to 1-block/CU mega-tiles (R11:
// 310 cyc/wave compute cannot cover ~1150 cyc/K-tile staging — pipeline is load-
// dominated by construction). Latency hiding here = blocks/CU TLP. This structure
// is the verified plateau of the 2-barrier template (~13% MfmaUtil); the next step
// up requires the full 8-phase co-designed schedule, out of blind-round risk budget.
template<int EPI, bool QS>
__global__ __launch_bounds__(512) void gemm256(
    const short* __restrict__ A, const short* __restrict__ BT,
    const float* __restrict__ bias, void* __restrict__ Out,
    const void* __restrict__ P0, void* __restrict__ P1,
    int M, int N, int K)
{
    __shared__ short As[256 * 64];
    __shared__ short Bs[128 * 64];
    const int m0 = blockIdx.y * 256, n0 = blockIdx.x * 128;
    const int tid = threadIdx.x;
    const int wid = tid >> 6, lane = tid & 63;
    const int wm = wid >> 1, wn = wid & 1;           // 4M x 2N waves
    const int l15 = lane & 15, quad = lane >> 4;

    f32x4 acc[4][4];
    #pragma unroll
    for (int i = 0; i < 4; i++)
        #pragma unroll
        for (int j = 0; j < 4; j++) acc[i][j] = (f32x4){0.f, 0.f, 0.f, 0.f};

    const int trow = tid >> 3;                 // 0..63
    const int cs = tid & 7;
    const int gc = cs ^ (trow & 7);
    const short* Ag[4]; const short* Bg[2];
    #pragma unroll
    for (int j = 0; j < 4; j++) {
        int ar = m0 + j * 64 + trow; if (ar >= M) ar = M - 1;
        Ag[j] = A + (size_t)ar * K + gc * 8;
    }
    #pragma unroll
    for (int j = 0; j < 2; j++) {
        int br = n0 + j * 64 + trow; if (br >= N) br = N - 1;
        Bg[j] = BT + (size_t)br * K + gc * 8;
    }
    short* AsW[4]; short* BsW[2];
    #pragma unroll
    for (int j = 0; j < 4; j++) AsW[j] = &As[(j * 64 + wid * 8) * 64];
    #pragma unroll
    for (int j = 0; j < 2; j++) BsW[j] = &Bs[(j * 64 + wid * 8) * 64];

    int arow[4], brow[4];
    #pragma unroll
    for (int mt = 0; mt < 4; mt++) arow[mt] = wm * 64 + mt * 16 + l15;
    #pragma unroll
    for (int nt = 0; nt < 4; nt++) brow[nt] = wn * 64 + nt * 16 + l15;

    for (int ks = 0; ks < K; ks += 64) {
        #pragma unroll
        for (int j = 0; j < 4; j++) gload16(Ag[j] + ks, AsW[j]);
        #pragma unroll
        for (int j = 0; j < 2; j++) gload16(Bg[j] + ks, BsW[j]);
        __syncthreads();
        #pragma unroll
        for (int ko = 0; ko < 2; ko++) {
            short8 af[4], bf[4];
            #pragma unroll
            for (int mt = 0; mt < 4; mt++)
                af[mt] = *(const short8*)&As[arow[mt] * 64
                         + (((ko * 4 + quad) ^ (l15 & 7)) * 8)];
            #pragma unroll
            for (int nt = 0; nt < 4; nt++)
                bf[nt] = *(const short8*)&Bs[brow[nt] * 64
                         + (((ko * 4 + quad) ^ (l15 & 7)) * 8)];
            #pragma unroll
            for (int mt = 0; mt < 4; mt++)
                #pragma unroll
                for (int nt = 0; nt < 4; nt++)
                    acc[mt][nt] = __builtin_amdgcn_mfma_f32_16x16x32_bf16(
                        af[mt], bf[nt], acc[mt][nt], 0, 0, 0);
        }
        __syncthreads();
    }

    #pragma unroll
    for (int mt = 0; mt < 4; mt++) {
        #pragma unroll
        for (int nt = 0; nt < 4; nt++) {
            #pragma unroll
            for (int r = 0; r < 4; r++) {
                int row = m0 + wm * 64 + mt * 16 + quad * 4 + r;
                int col = n0 + wn * 64 + nt * 16 + l15;
                if (row >= M) continue;
                float v = acc[mt][nt][r] + bias[col];
                if (EPI == 0) {
                    if (QS && col < 384) v *= 0.17677669529663687f;
                    ((short*)Out)[(size_t)row * N + col] = f2b(v);
                } else if (EPI == 1) {
                    // GELU tanh form: v - v/(1+exp(1.5957691 v + 0.07135482 v^3))
                    float u2 = v * v;
                    float w  = v * fmaf(0.07135481633f, u2, 1.5957691216f);
                    float e  = __expf(w);
                    float t2 = __builtin_amdgcn_rcpf(1.0f + e);
                    v = v - v * t2;
                    ((short*)Out)[(size_t)row * N + col] = f2b(v);
                } else if (EPI == 2) {
                    int w = row / 344, n = row - w * 344;
                    if (n == 0) {
                        ((float*)P1)[(size_t)w * 384 + col] = v;
                    } else {
                        int t2 = n - 1;
                        int a = t2 / 49, rm = t2 - a * 49;
                        int bb = rm / 7, cc = rm - bb * 7;
                        int hw = w >> 3, ww = w & 7;
                        int s = (a < 4) ? a + 3 : a - 4;
                        int h = hw * 7 + bb + 3; if (h >= 56) h -= 56;
                        int wd = ww * 7 + cc + 3; if (wd >= 56) wd -= 56;
                        size_t td = (size_t)((s * 56 + h) * 56 + wd) * 384 + col;
                        // xnew stored bf16 (residual x stays fp32)
                        ((short*)Out)[td] = f2b(v + ((const float*)P0)[td]);
                    }
                } else {  // EPI 3: residual read from bf16 xnew
                    v += b2f(((const short*)P0)[(size_t)row * N + col]);
                    ((float*)Out)[(size_t)row * N + col] = v;
                }
            }
        }
    }
}

// -------- fused windowed attention, swapped-QK in-register softmax --------
// XCD-aware head-major remap (btfm slice fits XCD L2); btfm C-operand prefetch
// one kk ahead (named-register rotation); s_setprio around MFMA clusters (T5).
__global__ __launch_bounds__(256) void attn_kernel(
    const short* __restrict__ qkv, const float* __restrict__ btfm,
    short* __restrict__ attn_out)
{
    __shared__ short KT[352 * 32];   // 22528B permuted K rows, chunk-swizzled
    __shared__ short VT[32 * 360];   // 23040B V^T: [dd][key]
    const int orig = blockIdx.x;
    const int nid = (orig & 7) * 96 + (orig >> 3);   // bijective, 768 = 8*96
    const int head = nid >> 6, w = nid & 63;         // head-major within XCD chunk
    const int cls = (((w >> 3) == 7) ? 2 : 0) | (((w & 7) == 7) ? 1 : 0);
    const int tid = threadIdx.x;
    const int wid = tid >> 6, lane = tid & 63;
    const int l15 = lane & 15, quad = lane >> 4;
    const size_t base = (size_t)w * 344 * 1152 + head * 32;

    // stage K: row permutation + chunk XOR-swizzle (slot = ch ^ ((R>>1)&3))
    for (int c = tid; c < 352 * 4; c += 256) {
        int n = c >> 2, ch = c & 3;
        short8 v8 = (short8){0,0,0,0,0,0,0,0};
        if (n < 344) v8 = *(const short8*)&qkv[base + 384 + (size_t)n * 1152 + ch * 8];
        int j32 = n & 31, kk = n >> 5;
        int R = kk * 32 + ((j32 >> 2) & 1) * 16 + ((j32 >> 3) << 2) + (j32 & 3);
        *(short8*)&KT[R * 32 + ((ch ^ ((R >> 1) & 3)) * 8)] = v8;
    }
    // stage V^T: vectorized 16B global reads, scalar transpose writes
    for (int e = tid; e < 344 * 4; e += 256) {
        int key = e >> 2, g = (e & 3) * 8;
        short8 v8 = *(const short8*)&qkv[base + 768 + (size_t)key * 1152 + g];
        #pragma unroll
        for (int i = 0; i < 8; i++) VT[(g + i) * 360 + key] = v8[i];
    }
    for (int e = tid; e < 8 * 32; e += 256) {
        int key = 344 + (e >> 5), dd = e & 31;
        VT[dd * 360 + key] = 0;
    }
    __syncthreads();

    const float* bh = btfm + (size_t)(cls * 12 + head) * (22 * 11 * 2 * 256);
    const int swq = (l15 >> 1) & 3;
    const int kOff = l15 * 32 + ((quad ^ swq) * 8);   // + kk*1024 + h*512

    for (int j = wid; j < 11; j += 4) {
        const int rtA = 2 * j, rtB = rtA + 1;
        const int qrA = rtA * 16 + l15;                  // <= 335, valid
        int qrB = rtB * 16 + l15; if (qrB > 343) qrB = 343;
        short8 afA = *(const short8*)&qkv[base + (size_t)qrA * 1152 + quad * 8];
        short8 afB = *(const short8*)&qkv[base + (size_t)qrB * 1152 + quad * 8];

        f32x4 oA0 = {0,0,0,0}, oA1 = {0,0,0,0}, oB0 = {0,0,0,0}, oB1 = {0,0,0,0};
        float lA = 0.f, lB = 0.f;
        const float* bhA = bh + (size_t)rtA * (11 * 2 * 256) + lane * 4;
        const float* bhB = bh + (size_t)rtB * (11 * 2 * 256) + lane * 4;

        // prefetch kk=0 bias fragments
        f32x4 nA0 = *(const f32x4*)&bhA[0];
        f32x4 nA1 = *(const f32x4*)&bhA[256];
        f32x4 nB0 = *(const f32x4*)&bhB[0];
        f32x4 nB1 = *(const f32x4*)&bhB[256];

        for (int kk = 0; kk < 11; kk++) {
            f32x4 cA0 = nA0, cA1 = nA1, cB0 = nB0, cB1 = nB1;
            int kn = (kk < 10) ? kk + 1 : 10;   // clamped prefetch index
            nA0 = *(const f32x4*)&bhA[(kn * 2 + 0) * 256];
            nA1 = *(const f32x4*)&bhA[(kn * 2 + 1) * 256];
            nB0 = *(const f32x4*)&bhB[(kn * 2 + 0) * 256];
            nB1 = *(const f32x4*)&bhB[(kn * 2 + 1) * 256];

            short8 k0 = *(const short8*)&KT[kk * 1024 + kOff];
            short8 k1 = *(const short8*)&KT[kk * 1024 + 512 + kOff];
            // swapped QK^T: output col=l15=q-row, reg r = key kk*32+8*quad+4*h+r
            __builtin_amdgcn_s_setprio(1);
            f32x4 sA0 = __builtin_amdgcn_mfma_f32_16x16x32_bf16(k0, afA, cA0, 0, 0, 0);
            f32x4 sA1 = __builtin_amdgcn_mfma_f32_16x16x32_bf16(k1, afA, cA1, 0, 0, 0);
            f32x4 sB0 = __builtin_amdgcn_mfma_f32_16x16x32_bf16(k0, afB, cB0, 0, 0, 0);
            f32x4 sB1 = __builtin_amdgcn_mfma_f32_16x16x32_bf16(k1, afB, cB1, 0, 0, 0);
            __builtin_amdgcn_s_setprio(0);

            float a0 = __expf(sA0[0]), a1 = __expf(sA0[1]);
            float a2 = __expf(sA0[2]), a3 = __expf(sA0[3]);
            float a4 = __expf(sA1[0]), a5 = __expf(sA1[1]);
            float a6 = __expf(sA1[2]), a7 = __expf(sA1[3]);
            lA += ((a0 + a1) + (a2 + a3)) + ((a4 + a5) + (a6 + a7));
            i32x4 pkA;
            pkA[0] = cvtpk(a0, a1); pkA[1] = cvtpk(a2, a3);
            pkA[2] = cvtpk(a4, a5); pkA[3] = cvtpk(a6, a7);
            short8 paA = __builtin_bit_cast(short8, pkA);

            float b0 = __expf(sB0[0]), b1 = __expf(sB0[1]);
            float b2 = __expf(sB0[2]), b3 = __expf(sB0[3]);
            float b4 = __expf(sB1[0]), b5 = __expf(sB1[1]);
            float b6 = __expf(sB1[2]), b7 = __expf(sB1[3]);
            lB += ((b0 + b1) + (b2 + b3)) + ((b4 + b5) + (b6 + b7));
            i32x4 pkB;
            pkB[0] = cvtpk(b0, b1); pkB[1] = cvtpk(b2, b3);
            pkB[2] = cvtpk(b4, b5); pkB[3] = cvtpk(b6, b7);
            short8 paB = __builtin_bit_cast(short8, pkB);

            short8 v0 = *(const short8*)&VT[l15 * 360 + kk * 32 + quad * 8];
            short8 v1 = *(const short8*)&VT[(16 + l15) * 360 + kk * 32 + quad * 8];
            __builtin_amdgcn_s_setprio(1);
            oA0 = __builtin_amdgcn_mfma_f32_16x16x32_bf16(paA, v0, oA0, 0, 0, 0);
            oA1 = __builtin_amdgcn_mfma_f32_16x16x32_bf16(paA, v1, oA1, 0, 0, 0);
            oB0 = __builtin_amdgcn_mfma_f32_16x16x32_bf16(paB, v0, oB0, 0, 0, 0);
            oB1 = __builtin_amdgcn_mfma_f32_16x16x32_bf16(paB, v1, oB1, 0, 0, 0);
            __builtin_amdgcn_s_setprio(0);
        }

        // denominator: lane l15 holds partial for q-row rt*16+l15; reduce quads
        lA += __shfl_xor(lA, 16); lA += __shfl_xor(lA, 32);
        lB += __shfl_xor(lB, 16); lB += __shfl_xor(lB, 32);
        float iA = 1.0f / lA, iB = 1.0f / lB;
        #pragma unroll
        for (int r = 0; r < 4; r++) {
            int rowA = rtA * 16 + quad * 4 + r;          // < 344 always
            float nA = __shfl(iA, quad * 4 + r);
            float nB = __shfl(iB, quad * 4 + r);
            size_t obA = ((size_t)w * 344 + rowA) * 384 + head * 32;
            attn_out[obA + l15] = f2b(oA0[r] * nA);
            attn_out[obA + 16 + l15] = f2b(oA1[r] * nA);
            int rowB = rowA + 16;
            if (rowB < 344) {
                size_t obB = ((size_t)w * 344 + rowB) * 384 + head * 32;
                attn_out[obB + l15] = f2b(oB0[r] * nB);
                attn_out[obB + 16 + l15] = f2b(oB1[r] * nB);
            }
        }
    }
}

extern "C" void kernel_launch(void* const* d_in, const int* in_sizes, int n_in,
                              void* d_out, int out_size, void* d_ws, size_t ws_size,
                              hipStream_t stream)
{
    const float* x      = (const float*)d_in[0];
    const float* gt     = (const float*)d_in[1];
    const float* n1g    = (const float*)d_in[2];
    const float* n1b    = (const float*)d_in[3];
    const float* qkv_w  = (const float*)d_in[4];
    const float* qkv_b  = (const float*)d_in[5];
    const float* btab   = (const float*)d_in[6];
    const float* proj_w = (const float*)d_in[7];
    const float* proj_b = (const float*)d_in[8];
    const float* n2g    = (const float*)d_in[9];
    const float* n2b    = (const float*)d_in[10];
    const float* fc1_w  = (const float*)d_in[11];
    const float* fc1_b  = (const float*)d_in[12];
    const float* fc2_w  = (const float*)d_in[13];
    const float* fc2_b  = (const float*)d_in[14];

    char* ws = (char*)d_ws;
    short* wt_qkv  = (short*)(ws + 0);          //  1152x384 bf16
    short* wt_proj = (short*)(ws + 884736);     //   384x384 bf16
    short* wt_fc1  = (short*)(ws + 1179648);    //  1536x384 bf16
    short* wt_fc2  = (short*)(ws + 2359296);    //   384x1536 bf16
    short* xc      = (short*)(ws + 3538944);    // 22016x384 bf16
    short* qkvb    = (short*)(ws + 20447232);   // 22016x1152 bf16
    short* attn_o  = xc;                        // reuse (xc dead after qkv GEMM)
    short* h1      = (short*)(ws + 3538944);    // 21952x1536 bf16 (reuse xc region)
    short* xnew    = (short*)(ws + 71172096);   // 21952x384 bf16
    float* btfm    = (float*)(ws + 71172096);   // 23.8MB fp32 (dead before xnew)
    short* xnorm   = (short*)(ws + 104890368);  // 21952x384 bf16

    float* outx  = (float*)d_out;
    float* outgt = outx + (size_t)21952 * 384;

    prep_kernel<<<dim3(13040), 256, 0, stream>>>(
        qkv_w, proj_w, fc1_w, fc2_w, wt_qkv, wt_proj, wt_fc1, wt_fc2,
        btab, btfm, x, gt, n1g, n1b, xc);

    gemm256<0, true><<<dim3(9, 86), 512, 0, stream>>>(xc, wt_qkv, qkv_b, qkvb,
                                                      nullptr, nullptr, 22016, 1152, 384);

    attn_kernel<<<dim3(768), 256, 0, stream>>>(qkvb, btfm, attn_o);

    gemm256<2, false><<<dim3(3, 86), 512, 0, stream>>>(attn_o, wt_proj, proj_b, xnew,
                                                       x, outgt, 22016, 384, 384);

    ln2_kernel<<<dim3(5488), 256, 0, stream>>>(xnew, n2g, n2b, xnorm);

    gemm256<1, false><<<dim3(12, 86), 512, 0, stream>>>(xnorm, wt_fc1, fc1_b, h1,
                                                        nullptr, nullptr, 21952, 1536, 384);

    gemm256<3, false><<<dim3(3, 86), 512, 0, stream>>>(h1, wt_fc2, fc2_b, outx,
                                                       xnew, nullptr, 21952, 384, 1536);
}

// Round 13
// 365.134 us; speedup vs baseline: 1.1692x; 1.0807x over previous
//
#include <hip/hip_runtime.h>
#include <math.h>

typedef __attribute__((ext_vector_type(8))) short short8;
typedef __attribute__((ext_vector_type(4))) float f32x4;
typedef __attribute__((ext_vector_type(4))) int i32x4;

__device__ __forceinline__ float b2f(short s) {
    unsigned u = ((unsigned)(unsigned short)s) << 16;
    return __builtin_bit_cast(float, u);
}
__device__ __forceinline__ short f2b(float f) {
    unsigned u = __builtin_bit_cast(unsigned, f);
    u += 0x7FFFu + ((u >> 16) & 1u);
    return (short)(u >> 16);
}
// packed f32x2 -> bf16x2 (RNE), gfx950 has no builtin for this (guide T12)
__device__ __forceinline__ int cvtpk(float lo, float hi) {
    int d;
    asm("v_cvt_pk_bf16_f32 %0, %1, %2" : "=v"(d) : "v"(lo), "v"(hi));
    return d;
}
// async global->LDS, 16B per lane; lds base must be wave-uniform
__device__ __forceinline__ void gload16(const void* g, void* l) {
    __builtin_amdgcn_global_load_lds(
        (const __attribute__((address_space(1))) unsigned int*)g,
        (__attribute__((address_space(3))) unsigned int*)l, 16, 0, 0);
}

// ================= fused preprocessing: 4 transposes + bias_pre + ln1 =================
__device__ __forceinline__ void transpose_body(
    const float* __restrict__ src, short* __restrict__ dst,
    int K, int N, int bx, int by, short (*tile)[33])
{
    const int kt = by * 32, nt = bx * 32;
    const int tx = threadIdx.x & 31, ty = threadIdx.x >> 5;
    #pragma unroll
    for (int i = 0; i < 4; i++) {
        int k = kt + ty + 8 * i, n = nt + tx;
        short v = 0;
        if (k < K && n < N) v = f2b(src[(size_t)k * N + n]);
        tile[ty + 8 * i][tx] = v;
    }
    __syncthreads();
    #pragma unroll
    for (int i = 0; i < 4; i++) {
        int n = nt + ty + 8 * i, k = kt + tx;
        if (n < N && k < K) dst[(size_t)n * K + k] = tile[tx][ty + 8 * i];
    }
}

// bias+mask in SWAPPED-QK C-fragment layout:
// btfm[cls][head][rt][kk][h][lane][4]; q-row i = rt*16+(lane&15),
// key j = kk*32 + 8*(lane>>4) + 4*h + r; -100 when shift-groups differ.
__device__ __forceinline__ void bias_body(const float* __restrict__ btab,
                                          float* __restrict__ btf, int blk)
{
    int idx = blk * 256 + threadIdx.x;           // over 4*12*22*11*2*64
    int lane = idx & 63; int rem = idx >> 6;
    int h = rem & 1; rem >>= 1;
    int kk = rem % 11; rem /= 11;
    int rt = rem % 22; rem /= 22;
    int head = rem % 12; int cls = rem / 12;
    int i = rt * 16 + (lane & 15);
    int jbase = kk * 32 + (lane >> 4) * 8 + h * 4;
    f32x4 out;
    #pragma unroll
    for (int r = 0; r < 4; r++) {
        int jj = jbase + r;
        float v;
        if (jj >= 344) v = -1e30f;
        else if (i >= 344 || i == 0 || jj == 0) v = 0.f;
        else {
            int ti = i - 1, tj = jj - 1;
            int ai = ti / 49, bi = (ti % 49) / 7, ci = ti % 7;
            int aj = tj / 49, bj = (tj % 49) / 7, cj = tj % 7;
            int id3 = (ai - aj + 6) * 20 + (bi - bj + 6) * 13 + (ci - cj + 6);
            v = btab[id3 * 12 + head];
            int gsi = (ai < 4) ? 1 : 2, gsj = (aj < 4) ? 1 : 2;
            int ghi = (cls & 2) ? ((bi < 4) ? 1 : 2) : 0;
            int ghj = (cls & 2) ? ((bj < 4) ? 1 : 2) : 0;
            int gwi = (cls & 1) ? ((ci < 4) ? 1 : 2) : 0;
            int gwj = (cls & 1) ? ((cj < 4) ? 1 : 2) : 0;
            if (gsi != gsj || ghi != ghj || gwi != gwj) v -= 100.f;
        }
        out[r] = v;
    }
    *(f32x4*)&btf[(size_t)idx * 4] = out;
}

__device__ __forceinline__ void ln1_body(
    const float* __restrict__ x, const float* __restrict__ gt,
    const float* __restrict__ g, const float* __restrict__ b,
    short* __restrict__ xc, int blk)
{
    int wid = threadIdx.x >> 6, lane = threadIdx.x & 63;
    int r = blk * 4 + wid;
    int w = r / 344, n = r - w * 344;
    if (n == 0) {
        #pragma unroll
        for (int i = 0; i < 6; i++) {
            int c = lane + i * 64;
            xc[(size_t)r * 384 + c] = f2b(gt[(size_t)w * 384 + c]);
        }
        return;
    }
    int t = n - 1;
    int a = t / 49, rm = t - a * 49, bb = rm / 7, cc = rm - bb * 7;
    int hw = w >> 3, ww = w & 7;
    int s = (a < 4) ? a + 3 : a - 4;
    int h = hw * 7 + bb + 3; if (h >= 56) h -= 56;
    int wd = ww * 7 + cc + 3; if (wd >= 56) wd -= 56;
    const float* row = x + (size_t)((s * 56 + h) * 56 + wd) * 384;
    float v[6]; float sum = 0.f;
    #pragma unroll
    for (int i = 0; i < 6; i++) { v[i] = row[lane + i * 64]; sum += v[i]; }
    #pragma unroll
    for (int off = 32; off >= 1; off >>= 1) sum += __shfl_xor(sum, off);
    float mu = sum * (1.0f / 384.0f);
    float vs = 0.f;
    #pragma unroll
    for (int i = 0; i < 6; i++) { float d = v[i] - mu; vs += d * d; }
    #pragma unroll
    for (int off = 32; off >= 1; off >>= 1) vs += __shfl_xor(vs, off);
    float rstd = rsqrtf(vs * (1.0f / 384.0f) + 1e-5f);
    #pragma unroll
    for (int i = 0; i < 6; i++) {
        int c = lane + i * 64;
        float o = (v[i] - mu) * rstd * g[c] + b[c];
        xc[(size_t)r * 384 + c] = f2b(o);
    }
}

// block ranges: [0,432) qkvT | [432,576) projT | [576,1152) fc1T | [1152,1728) fc2T
//             | [1728,7536) bias | [7536,13040) ln1
__global__ __launch_bounds__(256) void prep_kernel(
    const float* __restrict__ qkv_w, const float* __restrict__ proj_w,
    const float* __restrict__ fc1_w, const float* __restrict__ fc2_w,
    short* __restrict__ wt_qkv, short* __restrict__ wt_proj,
    short* __restrict__ wt_fc1, short* __restrict__ wt_fc2,
    const float* __restrict__ btab, float* __restrict__ btf,
    const float* __restrict__ x, const float* __restrict__ gt,
    const float* __restrict__ n1g, const float* __restrict__ n1b,
    short* __restrict__ xc)
{
    __shared__ short tile[32][33];
    int b = blockIdx.x;
    if (b < 432)  { transpose_body(qkv_w,  wt_qkv,  384, 1152, b % 36, b / 36, tile); return; }
    b -= 432;
    if (b < 144)  { transpose_body(proj_w, wt_proj, 384,  384, b % 12, b / 12, tile); return; }
    b -= 144;
    if (b < 576)  { transpose_body(fc1_w,  wt_fc1,  384, 1536, b % 48, b / 48, tile); return; }
    b -= 576;
    if (b < 576)  { transpose_body(fc2_w,  wt_fc2, 1536,  384, b % 12, b / 12, tile); return; }
    b -= 576;
    if (b < 5808) { bias_body(btab, btf, b); return; }
    b -= 5808;
    ln1_body(x, gt, n1g, n1b, xc, b);
}

// ------------ LN2 over bf16 x_new, token-major, out bf16 ------------
__global__ __launch_bounds__(256) void ln2_kernel(
    const short* __restrict__ xn, const float* __restrict__ g,
    const float* __restrict__ b, short* __restrict__ out)
{
    int wid = threadIdx.x >> 6, lane = threadIdx.x & 63;
    int r = blockIdx.x * 4 + wid;
    const short* row = xn + (size_t)r * 384;
    float v[6]; float sum = 0.f;
    #pragma unroll
    for (int i = 0; i < 6; i++) { v[i] = b2f(row[lane + i * 64]); sum += v[i]; }
    #pragma unroll
    for (int off = 32; off >= 1; off >>= 1) sum += __shfl_xor(sum, off);
    float mu = sum * (1.0f / 384.0f);
    float vs = 0.f;
    #pragma unroll
    for (int i = 0; i < 6; i++) { float d = v[i] - mu; vs += d * d; }
    #pragma unroll
    for (int off = 32; off >= 1; off >>= 1) vs += __shfl_xor(vs, off);
    float rstd = rsqrtf(vs * (1.0f / 384.0f) + 1e-5f);
    #pragma unroll
    for (int i = 0; i < 6; i++) {
        int c = lane + i * 64;
        float o = (v[i] - mu) * rstd * g[c] + b[c];
        out[(size_t)r * 384 + c] = f2b(o);
    }
}

// ------- 256x128-tile bf16 MFMA GEMM, BK=64, single-buffer 2-barrier (R6 proven) -------
// NOTE (R1/R2/R7/R8/R11 post-mortems): do NOT double-buffer, do NOT graft counted-
// vmcnt pipelines, do NOT set min-waves, do NOT go to 1-block/CU mega-tiles.
// Latency hiding = blocks/CU TLP. R13: bijective XCD-chunked block remap (T1/m204)
// — 1D grid, each XCD owns a contiguous chunk of the N-fastest tile order, so an
// M-band's A-panel (192KB) is resolved within ONE XCD's L2 instead of fetched by
// ~8 XCDs (R12 counters: FETCH 69MB vs 18MB unique = ~4x re-fetch).
template<int EPI, bool QS>
__global__ __launch_bounds__(512) void gemm256(
    const short* __restrict__ A, const short* __restrict__ BT,
    const float* __restrict__ bias, void* __restrict__ Out,
    const void* __restrict__ P0, void* __restrict__ P1,
    int M, int N, int K)
{
    __shared__ short As[256 * 64];
    __shared__ short Bs[128 * 64];
    // XCD-chunked bijection (m204): xcd = orig%8 keeps its HW round-robin slot;
    // wgid walks a contiguous chunk of the tile space per XCD.
    const int nwg = gridDim.x;
    const int orig = blockIdx.x;
    const int q8 = nwg >> 3, r8 = nwg & 7;
    const int xcd = orig & 7, cidx = orig >> 3;
    const int wgid = (xcd < r8 ? xcd * (q8 + 1)
                               : r8 * (q8 + 1) + (xcd - r8) * q8) + cidx;
    const int NX = (N + 127) >> 7;
    const int bx = wgid % NX, by = wgid / NX;
    const int m0 = by * 256, n0 = bx * 128;
    const int tid = threadIdx.x;
    const int wid = tid >> 6, lane = tid & 63;
    const int wm = wid >> 1, wn = wid & 1;           // 4M x 2N waves
    const int l15 = lane & 15, quad = lane >> 4;

    f32x4 acc[4][4];
    #pragma unroll
    for (int i = 0; i < 4; i++)
        #pragma unroll
        for (int j = 0; j < 4; j++) acc[i][j] = (f32x4){0.f, 0.f, 0.f, 0.f};

    const int trow = tid >> 3;                 // 0..63
    const int cs = tid & 7;
    const int gc = cs ^ (trow & 7);
    const short* Ag[4]; const short* Bg[2];
    #pragma unroll
    for (int j = 0; j < 4; j++) {
        int ar = m0 + j * 64 + trow; if (ar >= M) ar = M - 1;
        Ag[j] = A + (size_t)ar * K + gc * 8;
    }
    #pragma unroll
    for (int j = 0; j < 2; j++) {
        int br = n0 + j * 64 + trow; if (br >= N) br = N - 1;
        Bg[j] = BT + (size_t)br * K + gc * 8;
    }
    short* AsW[4]; short* BsW[2];
    #pragma unroll
    for (int j = 0; j < 4; j++) AsW[j] = &As[(j * 64 + wid * 8) * 64];
    #pragma unroll
    for (int j = 0; j < 2; j++) BsW[j] = &Bs[(j * 64 + wid * 8) * 64];

    int arow[4], brow[4];
    #pragma unroll
    for (int mt = 0; mt < 4; mt++) arow[mt] = wm * 64 + mt * 16 + l15;
    #pragma unroll
    for (int nt = 0; nt < 4; nt++) brow[nt] = wn * 64 + nt * 16 + l15;

    for (int ks = 0; ks < K; ks += 64) {
        #pragma unroll
        for (int j = 0; j < 4; j++) gload16(Ag[j] + ks, AsW[j]);
        #pragma unroll
        for (int j = 0; j < 2; j++) gload16(Bg[j] + ks, BsW[j]);
        __syncthreads();
        #pragma unroll
        for (int ko = 0; ko < 2; ko++) {
            short8 af[4], bf[4];
            #pragma unroll
            for (int mt = 0; mt < 4; mt++)
                af[mt] = *(const short8*)&As[arow[mt] * 64
                         + (((ko * 4 + quad) ^ (l15 & 7)) * 8)];
            #pragma unroll
            for (int nt = 0; nt < 4; nt++)
                bf[nt] = *(const short8*)&Bs[brow[nt] * 64
                         + (((ko * 4 + quad) ^ (l15 & 7)) * 8)];
            #pragma unroll
            for (int mt = 0; mt < 4; mt++)
                #pragma unroll
                for (int nt = 0; nt < 4; nt++)
                    acc[mt][nt] = __builtin_amdgcn_mfma_f32_16x16x32_bf16(
                        af[mt], bf[nt], acc[mt][nt], 0, 0, 0);
        }
        __syncthreads();
    }

    #pragma unroll
    for (int mt = 0; mt < 4; mt++) {
        #pragma unroll
        for (int nt = 0; nt < 4; nt++) {
            #pragma unroll
            for (int r = 0; r < 4; r++) {
                int row = m0 + wm * 64 + mt * 16 + quad * 4 + r;
                int col = n0 + wn * 64 + nt * 16 + l15;
                if (row >= M) continue;
                float v = acc[mt][nt][r] + bias[col];
                if (EPI == 0) {
                    if (QS && col < 384) v *= 0.17677669529663687f;
                    ((short*)Out)[(size_t)row * N + col] = f2b(v);
                } else if (EPI == 1) {
                    // GELU tanh form: v - v/(1+exp(1.5957691 v + 0.07135482 v^3))
                    float u2 = v * v;
                    float w  = v * fmaf(0.07135481633f, u2, 1.5957691216f);
                    float e  = __expf(w);
                    float t2 = __builtin_amdgcn_rcpf(1.0f + e);
                    v = v - v * t2;
                    ((short*)Out)[(size_t)row * N + col] = f2b(v);
                } else if (EPI == 2) {
                    int w = row / 344, n = row - w * 344;
                    if (n == 0) {
                        ((float*)P1)[(size_t)w * 384 + col] = v;
                    } else {
                        int t2 = n - 1;
                        int a = t2 / 49, rm = t2 - a * 49;
                        int bb = rm / 7, cc = rm - bb * 7;
                        int hw = w >> 3, ww = w & 7;
                        int s = (a < 4) ? a + 3 : a - 4;
                        int h = hw * 7 + bb + 3; if (h >= 56) h -= 56;
                        int wd = ww * 7 + cc + 3; if (wd >= 56) wd -= 56;
                        size_t td = (size_t)((s * 56 + h) * 56 + wd) * 384 + col;
                        // xnew stored bf16 (residual x stays fp32)
                        ((short*)Out)[td] = f2b(v + ((const float*)P0)[td]);
                    }
                } else {  // EPI 3: residual read from bf16 xnew
                    v += b2f(((const short*)P0)[(size_t)row * N + col]);
                    ((float*)Out)[(size_t)row * N + col] = v;
                }
            }
        }
    }
}

// -------- fused windowed attention, swapped-QK in-register softmax --------
// XCD-aware head-major remap (btfm slice fits XCD L2); btfm C-operand prefetch
// one kk ahead (named-register rotation); s_setprio around MFMA clusters (T5).
__global__ __launch_bounds__(256) void attn_kernel(
    const short* __restrict__ qkv, const float* __restrict__ btfm,
    short* __restrict__ attn_out)
{
    __shared__ short KT[352 * 32];   // 22528B permuted K rows, chunk-swizzled
    __shared__ short VT[32 * 360];   // 23040B V^T: [dd][key]
    const int orig = blockIdx.x;
    const int nid = (orig & 7) * 96 + (orig >> 3);   // bijective, 768 = 8*96
    const int head = nid >> 6, w = nid & 63;         // head-major within XCD chunk
    const int cls = (((w >> 3) == 7) ? 2 : 0) | (((w & 7) == 7) ? 1 : 0);
    const int tid = threadIdx.x;
    const int wid = tid >> 6, lane = tid & 63;
    const int l15 = lane & 15, quad = lane >> 4;
    const size_t base = (size_t)w * 344 * 1152 + head * 32;

    // stage K: row permutation + chunk XOR-swizzle (slot = ch ^ ((R>>1)&3))
    for (int c = tid; c < 352 * 4; c += 256) {
        int n = c >> 2, ch = c & 3;
        short8 v8 = (short8){0,0,0,0,0,0,0,0};
        if (n < 344) v8 = *(const short8*)&qkv[base + 384 + (size_t)n * 1152 + ch * 8];
        int j32 = n & 31, kk = n >> 5;
        int R = kk * 32 + ((j32 >> 2) & 1) * 16 + ((j32 >> 3) << 2) + (j32 & 3);
        *(short8*)&KT[R * 32 + ((ch ^ ((R >> 1) & 3)) * 8)] = v8;
    }
    // stage V^T: vectorized 16B global reads, scalar transpose writes
    for (int e = tid; e < 344 * 4; e += 256) {
        int key = e >> 2, g = (e & 3) * 8;
        short8 v8 = *(const short8*)&qkv[base + 768 + (size_t)key * 1152 + g];
        #pragma unroll
        for (int i = 0; i < 8; i++) VT[(g + i) * 360 + key] = v8[i];
    }
    for (int e = tid; e < 8 * 32; e += 256) {
        int key = 344 + (e >> 5), dd = e & 31;
        VT[dd * 360 + key] = 0;
    }
    __syncthreads();

    const float* bh = btfm + (size_t)(cls * 12 + head) * (22 * 11 * 2 * 256);
    const int swq = (l15 >> 1) & 3;
    const int kOff = l15 * 32 + ((quad ^ swq) * 8);   // + kk*1024 + h*512

    for (int j = wid; j < 11; j += 4) {
        const int rtA = 2 * j, rtB = rtA + 1;
        const int qrA = rtA * 16 + l15;                  // <= 335, valid
        int qrB = rtB * 16 + l15; if (qrB > 343) qrB = 343;
        short8 afA = *(const short8*)&qkv[base + (size_t)qrA * 1152 + quad * 8];
        short8 afB = *(const short8*)&qkv[base + (size_t)qrB * 1152 + quad * 8];

        f32x4 oA0 = {0,0,0,0}, oA1 = {0,0,0,0}, oB0 = {0,0,0,0}, oB1 = {0,0,0,0};
        float lA = 0.f, lB = 0.f;
        const float* bhA = bh + (size_t)rtA * (11 * 2 * 256) + lane * 4;
        const float* bhB = bh + (size_t)rtB * (11 * 2 * 256) + lane * 4;

        // prefetch kk=0 bias fragments
        f32x4 nA0 = *(const f32x4*)&bhA[0];
        f32x4 nA1 = *(const f32x4*)&bhA[256];
        f32x4 nB0 = *(const f32x4*)&bhB[0];
        f32x4 nB1 = *(const f32x4*)&bhB[256];

        for (int kk = 0; kk < 11; kk++) {
            f32x4 cA0 = nA0, cA1 = nA1, cB0 = nB0, cB1 = nB1;
            int kn = (kk < 10) ? kk + 1 : 10;   // clamped prefetch index
            nA0 = *(const f32x4*)&bhA[(kn * 2 + 0) * 256];
            nA1 = *(const f32x4*)&bhA[(kn * 2 + 1) * 256];
            nB0 = *(const f32x4*)&bhB[(kn * 2 + 0) * 256];
            nB1 = *(const f32x4*)&bhB[(kn * 2 + 1) * 256];

            short8 k0 = *(const short8*)&KT[kk * 1024 + kOff];
            short8 k1 = *(const short8*)&KT[kk * 1024 + 512 + kOff];
            // swapped QK^T: output col=l15=q-row, reg r = key kk*32+8*quad+4*h+r
            __builtin_amdgcn_s_setprio(1);
            f32x4 sA0 = __builtin_amdgcn_mfma_f32_16x16x32_bf16(k0, afA, cA0, 0, 0, 0);
            f32x4 sA1 = __builtin_amdgcn_mfma_f32_16x16x32_bf16(k1, afA, cA1, 0, 0, 0);
            f32x4 sB0 = __builtin_amdgcn_mfma_f32_16x16x32_bf16(k0, afB, cB0, 0, 0, 0);
            f32x4 sB1 = __builtin_amdgcn_mfma_f32_16x16x32_bf16(k1, afB, cB1, 0, 0, 0);
            __builtin_amdgcn_s_setprio(0);

            float a0 = __expf(sA0[0]), a1 = __expf(sA0[1]);
            float a2 = __expf(sA0[2]), a3 = __expf(sA0[3]);
            float a4 = __expf(sA1[0]), a5 = __expf(sA1[1]);
            float a6 = __expf(sA1[2]), a7 = __expf(sA1[3]);
            lA += ((a0 + a1) + (a2 + a3)) + ((a4 + a5) + (a6 + a7));
            i32x4 pkA;
            pkA[0] = cvtpk(a0, a1); pkA[1] = cvtpk(a2, a3);
            pkA[2] = cvtpk(a4, a5); pkA[3] = cvtpk(a6, a7);
            short8 paA = __builtin_bit_cast(short8, pkA);

            float b0 = __expf(sB0[0]), b1 = __expf(sB0[1]);
            float b2 = __expf(sB0[2]), b3 = __expf(sB0[3]);
            float b4 = __expf(sB1[0]), b5 = __expf(sB1[1]);
            float b6 = __expf(sB1[2]), b7 = __expf(sB1[3]);
            lB += ((b0 + b1) + (b2 + b3)) + ((b4 + b5) + (b6 + b7));
            i32x4 pkB;
            pkB[0] = cvtpk(b0, b1); pkB[1] = cvtpk(b2, b3);
            pkB[2] = cvtpk(b4, b5); pkB[3] = cvtpk(b6, b7);
            short8 paB = __builtin_bit_cast(short8, pkB);

            short8 v0 = *(const short8*)&VT[l15 * 360 + kk * 32 + quad * 8];
            short8 v1 = *(const short8*)&VT[(16 + l15) * 360 + kk * 32 + quad * 8];
            __builtin_amdgcn_s_setprio(1);
            oA0 = __builtin_amdgcn_mfma_f32_16x16x32_bf16(paA, v0, oA0, 0, 0, 0);
            oA1 = __builtin_amdgcn_mfma_f32_16x16x32_bf16(paA, v1, oA1, 0, 0, 0);
            oB0 = __builtin_amdgcn_mfma_f32_16x16x32_bf16(paB, v0, oB0, 0, 0, 0);
            oB1 = __builtin_amdgcn_mfma_f32_16x16x32_bf16(paB, v1, oB1, 0, 0, 0);
            __builtin_amdgcn_s_setprio(0);
        }

        // denominator: lane l15 holds partial for q-row rt*16+l15; reduce quads
        lA += __shfl_xor(lA, 16); lA += __shfl_xor(lA, 32);
        lB += __shfl_xor(lB, 16); lB += __shfl_xor(lB, 32);
        float iA = 1.0f / lA, iB = 1.0f / lB;
        #pragma unroll
        for (int r = 0; r < 4; r++) {
            int rowA = rtA * 16 + quad * 4 + r;          // < 344 always
            float nA = __shfl(iA, quad * 4 + r);
            float nB = __shfl(iB, quad * 4 + r);
            size_t obA = ((size_t)w * 344 + rowA) * 384 + head * 32;
            attn_out[obA + l15] = f2b(oA0[r] * nA);
            attn_out[obA + 16 + l15] = f2b(oA1[r] * nA);
            int rowB = rowA + 16;
            if (rowB < 344) {
                size_t obB = ((size_t)w * 344 + rowB) * 384 + head * 32;
                attn_out[obB + l15] = f2b(oB0[r] * nB);
                attn_out[obB + 16 + l15] = f2b(oB1[r] * nB);
            }
        }
    }
}

extern "C" void kernel_launch(void* const* d_in, const int* in_sizes, int n_in,
                              void* d_out, int out_size, void* d_ws, size_t ws_size,
                              hipStream_t stream)
{
    const float* x      = (const float*)d_in[0];
    const float* gt     = (const float*)d_in[1];
    const float* n1g    = (const float*)d_in[2];
    const float* n1b    = (const float*)d_in[3];
    const float* qkv_w  = (const float*)d_in[4];
    const float* qkv_b  = (const float*)d_in[5];
    const float* btab   = (const float*)d_in[6];
    const float* proj_w = (const float*)d_in[7];
    const float* proj_b = (const float*)d_in[8];
    const float* n2g    = (const float*)d_in[9];
    const float* n2b    = (const float*)d_in[10];
    const float* fc1_w  = (const float*)d_in[11];
    const float* fc1_b  = (const float*)d_in[12];
    const float* fc2_w  = (const float*)d_in[13];
    const float* fc2_b  = (const float*)d_in[14];

    char* ws = (char*)d_ws;
    short* wt_qkv  = (short*)(ws + 0);          //  1152x384 bf16
    short* wt_proj = (short*)(ws + 884736);     //   384x384 bf16
    short* wt_fc1  = (short*)(ws + 1179648);    //  1536x384 bf16
    short* wt_fc2  = (short*)(ws + 2359296);    //   384x1536 bf16
    short* xc      = (short*)(ws + 3538944);    // 22016x384 bf16
    short* qkvb    = (short*)(ws + 20447232);   // 22016x1152 bf16
    short* attn_o  = xc;                        // reuse (xc dead after qkv GEMM)
    short* h1      = (short*)(ws + 3538944);    // 21952x1536 bf16 (reuse xc region)
    short* xnew    = (short*)(ws + 71172096);   // 21952x384 bf16
    float* btfm    = (float*)(ws + 71172096);   // 23.8MB fp32 (dead before xnew)
    short* xnorm   = (short*)(ws + 104890368);  // 21952x384 bf16

    float* outx  = (float*)d_out;
    float* outgt = outx + (size_t)21952 * 384;

    prep_kernel<<<dim3(13040), 256, 0, stream>>>(
        qkv_w, proj_w, fc1_w, fc2_w, wt_qkv, wt_proj, wt_fc1, wt_fc2,
        btab, btfm, x, gt, n1g, n1b, xc);

    // R13: 1D grids with in-kernel XCD-chunked remap (tiles: NX = ceil(N/128),
    // NY = ceil(M/256), nwg = NX*NY)
    gemm256<0, true><<<dim3(774), 512, 0, stream>>>(xc, wt_qkv, qkv_b, qkvb,
                                                    nullptr, nullptr, 22016, 1152, 384);

    attn_kernel<<<dim3(768), 256, 0, stream>>>(qkvb, btfm, attn_o);

    gemm256<2, false><<<dim3(258), 512, 0, stream>>>(attn_o, wt_proj, proj_b, xnew,
                                                     x, outgt, 22016, 384, 384);

    ln2_kernel<<<dim3(5488), 256, 0, stream>>>(xnew, n2g, n2b, xnorm);

    gemm256<1, false><<<dim3(1032), 512, 0, stream>>>(xnorm, wt_fc1, fc1_b, h1,
                                                      nullptr, nullptr, 21952, 1536, 384);

    gemm256<3, false><<<dim3(258), 512, 0, stream>>>(h1, wt_fc2, fc2_b, outx,
                                                     xnew, nullptr, 21952, 384, 1536);
}